// Round 7
// baseline (880.936 us; speedup 1.0000x reference)
//
#include <hip/hip_runtime.h>
#include <hip/hip_bf16.h>

#define HID   51
#define MR    208          // 204 gate rows + y row (204) padded to 13 tiles of 16
#define SEQT  999
#define CH    111          // 999 = 9 * 111
#define NCH   9
#define EPB   8            // batch elements per block -> 512 blocks, 2 blocks/CU
#define XST   9            // x/y LDS stride (EPB+1)
#define NTW   13           // tile waves (one 16-row tile each)
#define NTH   896          // 13 tile waves + 1 x-service wave
#define BSTR  72           // bcol row stride in halves (144 B: 16B-aligned, free 2-way)

typedef __attribute__((ext_vector_type(8))) short  short8;   // 8 bf16 = 4 VGPRs
typedef __attribute__((ext_vector_type(4))) float  floatx4;

// A_ext[208][64] bf16, row r = 4u+gate, PRE-SCALED by -log2(e) (i,f,o) or
// -2*log2(e) (g) so the MFMA output is directly an exp2 argument.
//   rows 0..203: cols 0..50 <- W_hh[gate*51+u][k], col 51 <- W_ih[gate*51+u]
//   row  204   : cols 0..50 <- W_fc[k] UNSCALED  (y_{t-1} falls out of the MFMA)
__global__ void prep_kernel(const float* __restrict__ W_hh,
                            const float* __restrict__ W_ih,
                            const float* __restrict__ W_fc,
                            __hip_bfloat16* __restrict__ A_ext)
{
    const float K1 = 1.442695040889f;
    int idx = blockIdx.x * blockDim.x + threadIdx.x;
    if (idx >= MR * 64) return;
    int r = idx >> 6, k = idx & 63;
    int u = r >> 2, gate = r & 3;
    float v = 0.f;
    if (r == 204) {
        if (k < HID) v = W_fc[k];
    } else if (u < HID) {
        float s = (gate == 2) ? (-2.f * K1) : (-K1);
        if (k < HID)      v = s * W_hh[(gate * HID + u) * HID + k];
        else if (k == 51) v = s * W_ih[gate * HID + u];
    }
    A_ext[idx] = __float2bfloat16(v);
}

__launch_bounds__(NTH)
__global__ void lstm_mfma_kernel(const float* __restrict__ x,
                                 const float* __restrict__ b_ih,
                                 const float* __restrict__ b_hh,
                                 const float* __restrict__ b_fc,
                                 const __hip_bfloat16* __restrict__ A_ext,
                                 float* __restrict__ out)
{
    // bcol keeps the full 16-col MFMA layout; cols EPB..15 are dead (zeroed
    // once; whatever evolves there is finite and never leaves those cols).
    __shared__ __hip_bfloat16 bcol[2][16 * BSTR];
    __shared__ float x_lds[(CH + 1) * XST];   // +1 lookahead for row-51 prewrite
    __shared__ float y_lds[CH * XST];         // slot tt holds y[t0 + tt - 1]

    const int tid  = threadIdx.x;
    const int w    = tid >> 6;    // 0..12 tile waves, 13 = service wave
    const int lane = tid & 63;
    const int e    = lane & 15;   // MFMA col (e >= EPB lanes are dead weight)
    const int g4   = lane >> 4;   // lane group
    const int e0   = blockIdx.x * EPB;
    const int u    = 4 * w + g4;
    const bool tw  = (w < NTW);
    const bool uok = tw && (u < HID);
    const int wrow = uok ? u : 63;           // u==51 lanes dump into dead row 63
    const bool yln = (w == 12) && (g4 == 3) && (e < EPB); // y-row owners (live cols)

    const float K1  = 1.442695040889f;
    const float K2N = -2.885390081777f;      // -2*log2(e)

    short8  Afrag0 = {0,0,0,0,0,0,0,0}, Afrag1 = {0,0,0,0,0,0,0,0};
    floatx4 bq = {0.f, 0.f, 0.f, 0.f};       // stays 0 for u>=51 (incl. y row)
    float   cstS = 0.f;                       // cell state, pre-scaled by -2*log2(e)

    if (tw) {
        int m = w * 16 + e;
        Afrag0 = *(const short8*)&A_ext[m * 64 + g4 * 8];
        Afrag1 = *(const short8*)&A_ext[m * 64 + 32 + g4 * 8];
        if (u < HID) {
#pragma unroll
            for (int gg = 0; gg < 4; ++gg) {
                float s = (gg == 2) ? (-2.f * K1) : (-K1);
                bq[gg] = s * (b_ih[gg * HID + u] + b_hh[gg * HID + u]);
            }
        }
    }

    for (int i = tid; i < 16 * BSTR; i += NTH) {
        bcol[0][i] = __float2bfloat16(0.f);
        bcol[1][i] = __float2bfloat16(0.f);
    }
    __syncthreads();   // zero-init fully ordered before x0 seed
    if (tid < EPB)
        bcol[0][tid * BSTR + 51] = __float2bfloat16(x[(size_t)(e0 + tid) * SEQT]);
    const float bfc = b_fc[0];

    __syncthreads();

    for (int tc = 0; tc < NCH; ++tc) {
        const int t0 = tc * CH;
        for (int i2 = tid; i2 < (CH + 1) * EPB; i2 += NTH) {
            int ee = i2 / (CH + 1), tt = i2 % (CH + 1);
            int t = t0 + tt;
            x_lds[tt * XST + ee] = (t < SEQT) ? x[(size_t)(e0 + ee) * SEQT + t] : 0.f;
        }
        __syncthreads();

        for (int tt = 0; tt < CH; ++tt) {
            const int t  = t0 + tt;
            const int rp = t & 1, wp = rp ^ 1;

            if (tw) {
                short8 B0 = *(const short8*)&bcol[rp][e * BSTR + g4 * 8];
                short8 B1 = *(const short8*)&bcol[rp][e * BSTR + 32 + g4 * 8];

                floatx4 acc = __builtin_amdgcn_mfma_f32_16x16x32_bf16(Afrag0, B0, bq, 0, 0, 0);
                acc = __builtin_amdgcn_mfma_f32_16x16x32_bf16(Afrag1, B1, acc, 0, 0, 0);

                // fused sigmoid/tanh products: 5 exp2 + 3 rcp
                float Ei = __builtin_amdgcn_exp2f(acc[0]);
                float Ef = __builtin_amdgcn_exp2f(acc[1]);
                float Eg = __builtin_amdgcn_exp2f(acc[2]);
                float Eo = __builtin_amdgcn_exp2f(acc[3]);
                float sf  = __builtin_amdgcn_rcpf(1.f + Ef);
                float Rig = __builtin_amdgcn_rcpf(fmaf(Ei, Eg, (Ei + Eg) + 1.f));
                float term = (1.f - Eg) * Rig;            // sigma(i)*tanh(g)
                cstS = fmaf(sf, cstS, K2N * term);
                float Ec = __builtin_amdgcn_exp2f(cstS);
                float Roc = __builtin_amdgcn_rcpf(fmaf(Eo, Ec, (Eo + Ec) + 1.f));
                float h = (1.f - Ec) * Roc;               // sigma(o)*tanh(c)

                bcol[wp][e * BSTR + wrow] = __float2bfloat16(uok ? h : 0.f);
                if (yln) y_lds[tt * XST + e] = acc[0] + bfc;   // y[t-1], free
            } else if (lane < EPB) {
                // service wave: pre-write x_{t+1} into next buffer's row 51
                bcol[wp][lane * BSTR + 51] =
                    __float2bfloat16(x_lds[(tt + 1) * XST + lane]);
            }

            __syncthreads();   // the ONE barrier per step
        }
        __syncthreads();

        // flush y[t0-1 .. t0+CH-2] (slot tt <-> t0+tt-1); skip t = -1
        for (int i2 = tid; i2 < CH * EPB; i2 += NTH) {
            int ee = i2 / CH, tt = i2 % CH;
            int t = t0 + tt - 1;
            if (t >= 0)
                out[(size_t)(e0 + ee) * SEQT + t] = y_lds[tt * XST + ee];
        }
        __syncthreads();
    }

    // epilogue: y[998] from one extra MFMA pass over h_998 (in bcol[1])
    if (w == 12) {
        short8 B0 = *(const short8*)&bcol[1][e * BSTR + g4 * 8];
        short8 B1 = *(const short8*)&bcol[1][e * BSTR + 32 + g4 * 8];
        floatx4 acc = __builtin_amdgcn_mfma_f32_16x16x32_bf16(Afrag0, B0, bq, 0, 0, 0);
        acc = __builtin_amdgcn_mfma_f32_16x16x32_bf16(Afrag1, B1, acc, 0, 0, 0);
        if (g4 == 3 && e < EPB)
            out[(size_t)(e0 + e) * SEQT + (SEQT - 1)] = acc[0] + bfc;
    }
}

extern "C" void kernel_launch(void* const* d_in, const int* in_sizes, int n_in,
                              void* d_out, int out_size, void* d_ws, size_t ws_size,
                              hipStream_t stream) {
    const float* x    = (const float*)d_in[0];
    const float* W_ih = (const float*)d_in[1];
    const float* W_hh = (const float*)d_in[2];
    const float* b_ih = (const float*)d_in[3];
    const float* b_hh = (const float*)d_in[4];
    const float* W_fc = (const float*)d_in[5];
    const float* b_fc = (const float*)d_in[6];
    float* out = (float*)d_out;

    __hip_bfloat16* A_ext = (__hip_bfloat16*)d_ws;   // 208*64*2 = 26.6 KB

    prep_kernel<<<(MR * 64 + 255) / 256, 256, 0, stream>>>(W_hh, W_ih, W_fc, A_ext);
    lstm_mfma_kernel<<<4096 / EPB, NTH, 0, stream>>>(x, b_ih, b_hh,
                                                     b_fc, A_ext, out);
}

// Round 8
// 637.352 us; speedup vs baseline: 1.3822x; 1.3822x over previous
//
#include <hip/hip_runtime.h>
#include <hip/hip_bf16.h>

#define HID   51
#define MR    208          // 204 gate rows + y row (204) padded to 13 tiles of 16
#define SEQT  999
#define CH    111          // 999 = 9 * 111
#define NCH   9
#define EPB   8            // batch elements per block -> 512 blocks, 2 blocks/CU
#define XST   9            // x/y LDS stride (EPB+1)
#define NTH   448          // 7 waves: waves 0-5 = 2 tiles each, wave 6 = tile 12 + service
#define BSTR  72           // bcol row stride in halves (144 B: 16B-aligned, free 2-way)

typedef __attribute__((ext_vector_type(8))) short  short8;   // 8 bf16 = 4 VGPRs
typedef __attribute__((ext_vector_type(4))) float  floatx4;

// A_ext[208][64] bf16, row r = 4u+gate, PRE-SCALED by -log2(e) (i,f,o) or
// -2*log2(e) (g) so the MFMA output is directly an exp2 argument.
//   rows 0..203: cols 0..50 <- W_hh[gate*51+u][k], col 51 <- W_ih[gate*51+u]
//   row  204   : cols 0..50 <- W_fc[k] UNSCALED  (y_{t-1} falls out of the MFMA)
__global__ void prep_kernel(const float* __restrict__ W_hh,
                            const float* __restrict__ W_ih,
                            const float* __restrict__ W_fc,
                            __hip_bfloat16* __restrict__ A_ext)
{
    const float K1 = 1.442695040889f;
    int idx = blockIdx.x * blockDim.x + threadIdx.x;
    if (idx >= MR * 64) return;
    int r = idx >> 6, k = idx & 63;
    int u = r >> 2, gate = r & 3;
    float v = 0.f;
    if (r == 204) {
        if (k < HID) v = W_fc[k];
    } else if (u < HID) {
        float s = (gate == 2) ? (-2.f * K1) : (-K1);
        if (k < HID)      v = s * W_hh[(gate * HID + u) * HID + k];
        else if (k == 51) v = s * W_ih[gate * HID + u];
    }
    A_ext[idx] = __float2bfloat16(v);
}

__launch_bounds__(NTH)
__global__ void lstm_mfma_kernel(const float* __restrict__ x,
                                 const float* __restrict__ b_ih,
                                 const float* __restrict__ b_hh,
                                 const float* __restrict__ b_fc,
                                 const __hip_bfloat16* __restrict__ A_ext,
                                 float* __restrict__ out)
{
    // bcol keeps the full 16-col MFMA layout; cols EPB..15 are dead (zeroed
    // once; whatever evolves there is finite and never leaves those cols).
    __shared__ __hip_bfloat16 bcol[2][16 * BSTR];
    __shared__ float x_lds[(CH + 1) * XST];   // +1 lookahead for row-51 prewrite
    __shared__ float y_lds[CH * XST];         // slot tt holds y[t0 + tt - 1]

    const int tid  = threadIdx.x;
    const int w    = tid >> 6;    // 0..5 double-tile waves, 6 = tile-12 + service
    const int lane = tid & 63;
    const int e    = lane & 15;   // MFMA col (e >= EPB lanes are dead weight)
    const int g4   = lane >> 4;   // lane group
    const int e0   = blockIdx.x * EPB;
    const bool w6  = (w == 6);
    // wave 6 tile-12 units: 48+g4 for g4<3; g4==3 lanes own the y row (204)
    const int  uB6  = 48 + g4;
    const bool yln  = w6 && (g4 == 3) && (e < EPB);
    const bool xsv  = w6 && (g4 == 0) && (e < EPB);
    const int  wrow6 = (uB6 < HID) ? uB6 : 63;   // g4==3 -> dump row 63

    const float K1  = 1.442695040889f;
    const float K2N = -2.885390081777f;      // -2*log2(e)

    // waves 0-5: tiles Ta=2w, Tb=2w+1 -> units ua=8w+g4, ub=8w+4+g4 (all <48)
    short8  A0a = {0,0,0,0,0,0,0,0}, A1a = {0,0,0,0,0,0,0,0};
    short8  A0b = {0,0,0,0,0,0,0,0}, A1b = {0,0,0,0,0,0,0,0};
    floatx4 bqa = {0.f, 0.f, 0.f, 0.f}, bqb = {0.f, 0.f, 0.f, 0.f};
    float   csa = 0.f, csb = 0.f;            // cell states (pre-scaled)
    int ua = 0, ub = 0;

    if (!w6) {
        int Ta = 2 * w, Tb = 2 * w + 1;
        ua = 4 * Ta + g4; ub = 4 * Tb + g4;
        int ma = Ta * 16 + e, mb = Tb * 16 + e;
        A0a = *(const short8*)&A_ext[ma * 64 + g4 * 8];
        A1a = *(const short8*)&A_ext[ma * 64 + 32 + g4 * 8];
        A0b = *(const short8*)&A_ext[mb * 64 + g4 * 8];
        A1b = *(const short8*)&A_ext[mb * 64 + 32 + g4 * 8];
#pragma unroll
        for (int gg = 0; gg < 4; ++gg) {
            float s = (gg == 2) ? (-2.f * K1) : (-K1);
            bqa[gg] = s * (b_ih[gg * HID + ua] + b_hh[gg * HID + ua]);
            bqb[gg] = s * (b_ih[gg * HID + ub] + b_hh[gg * HID + ub]);
        }
    } else {
        int m = 12 * 16 + e;
        A0a = *(const short8*)&A_ext[m * 64 + g4 * 8];
        A1a = *(const short8*)&A_ext[m * 64 + 32 + g4 * 8];
        if (uB6 < HID) {
#pragma unroll
            for (int gg = 0; gg < 4; ++gg) {
                float s = (gg == 2) ? (-2.f * K1) : (-K1);
                bqa[gg] = s * (b_ih[gg * HID + uB6] + b_hh[gg * HID + uB6]);
            }
        }
    }

    for (int i = tid; i < 16 * BSTR; i += NTH) {
        bcol[0][i] = __float2bfloat16(0.f);
        bcol[1][i] = __float2bfloat16(0.f);
    }
    __syncthreads();   // zero-init fully ordered before x0 seed
    if (tid < EPB)
        bcol[0][tid * BSTR + 51] = __float2bfloat16(x[(size_t)(e0 + tid) * SEQT]);
    const float bfc = b_fc[0];

    __syncthreads();

    for (int tc = 0; tc < NCH; ++tc) {
        const int t0 = tc * CH;
        for (int i2 = tid; i2 < (CH + 1) * EPB; i2 += NTH) {
            int ee = i2 / (CH + 1), tt = i2 % (CH + 1);
            int t = t0 + tt;
            x_lds[tt * XST + ee] = (t < SEQT) ? x[(size_t)(e0 + ee) * SEQT + t] : 0.f;
        }
        __syncthreads();

        for (int tt = 0; tt < CH; ++tt) {
            const int t  = t0 + tt;
            const int rp = t & 1, wp = rp ^ 1;

            short8 B0 = *(const short8*)&bcol[rp][e * BSTR + g4 * 8];
            short8 B1 = *(const short8*)&bcol[rp][e * BSTR + 32 + g4 * 8];

            if (!w6) {
                // two independent tiles -> two ILP chains per wave
                floatx4 aa = __builtin_amdgcn_mfma_f32_16x16x32_bf16(A0a, B0, bqa, 0, 0, 0);
                floatx4 ab = __builtin_amdgcn_mfma_f32_16x16x32_bf16(A0b, B0, bqb, 0, 0, 0);
                aa = __builtin_amdgcn_mfma_f32_16x16x32_bf16(A1a, B1, aa, 0, 0, 0);
                ab = __builtin_amdgcn_mfma_f32_16x16x32_bf16(A1b, B1, ab, 0, 0, 0);

                float Eia = __builtin_amdgcn_exp2f(aa[0]);
                float Efa = __builtin_amdgcn_exp2f(aa[1]);
                float Ega = __builtin_amdgcn_exp2f(aa[2]);
                float Eoa = __builtin_amdgcn_exp2f(aa[3]);
                float Eib = __builtin_amdgcn_exp2f(ab[0]);
                float Efb = __builtin_amdgcn_exp2f(ab[1]);
                float Egb = __builtin_amdgcn_exp2f(ab[2]);
                float Eob = __builtin_amdgcn_exp2f(ab[3]);

                float sfa  = __builtin_amdgcn_rcpf(1.f + Efa);
                float sfb  = __builtin_amdgcn_rcpf(1.f + Efb);
                float Riga = __builtin_amdgcn_rcpf(fmaf(Eia, Ega, (Eia + Ega) + 1.f));
                float Rigb = __builtin_amdgcn_rcpf(fmaf(Eib, Egb, (Eib + Egb) + 1.f));
                csa = fmaf(sfa, csa, K2N * ((1.f - Ega) * Riga));
                csb = fmaf(sfb, csb, K2N * ((1.f - Egb) * Rigb));
                float Eca = __builtin_amdgcn_exp2f(csa);
                float Ecb = __builtin_amdgcn_exp2f(csb);
                float Roca = __builtin_amdgcn_rcpf(fmaf(Eoa, Eca, (Eoa + Eca) + 1.f));
                float Rocb = __builtin_amdgcn_rcpf(fmaf(Eob, Ecb, (Eob + Ecb) + 1.f));
                float ha = (1.f - Eca) * Roca;
                float hb = (1.f - Ecb) * Rocb;

                bcol[wp][e * BSTR + ua] = __float2bfloat16(ha);
                bcol[wp][e * BSTR + ub] = __float2bfloat16(hb);
            } else {
                floatx4 acc = __builtin_amdgcn_mfma_f32_16x16x32_bf16(A0a, B0, bqa, 0, 0, 0);
                acc = __builtin_amdgcn_mfma_f32_16x16x32_bf16(A1a, B1, acc, 0, 0, 0);

                float Ei = __builtin_amdgcn_exp2f(acc[0]);
                float Ef = __builtin_amdgcn_exp2f(acc[1]);
                float Eg = __builtin_amdgcn_exp2f(acc[2]);
                float Eo = __builtin_amdgcn_exp2f(acc[3]);
                float sf  = __builtin_amdgcn_rcpf(1.f + Ef);
                float Rig = __builtin_amdgcn_rcpf(fmaf(Ei, Eg, (Ei + Eg) + 1.f));
                csa = fmaf(sf, csa, K2N * ((1.f - Eg) * Rig));
                float Ec = __builtin_amdgcn_exp2f(csa);
                float Roc = __builtin_amdgcn_rcpf(fmaf(Eo, Ec, (Eo + Ec) + 1.f));
                float h = (1.f - Ec) * Roc;

                bcol[wp][e * BSTR + wrow6] = __float2bfloat16((uB6 < HID) ? h : 0.f);
                if (yln) y_lds[tt * XST + e] = acc[0] + bfc;   // y[t-1], free
                if (xsv) bcol[wp][e * BSTR + 51] =
                             __float2bfloat16(x_lds[(tt + 1) * XST + e]);
            }

            __syncthreads();   // the ONE barrier per step
        }
        __syncthreads();

        // flush y[t0-1 .. t0+CH-2] (slot tt <-> t0+tt-1); skip t = -1
        for (int i2 = tid; i2 < CH * EPB; i2 += NTH) {
            int ee = i2 / CH, tt = i2 % CH;
            int t = t0 + tt - 1;
            if (t >= 0)
                out[(size_t)(e0 + ee) * SEQT + t] = y_lds[tt * XST + ee];
        }
        __syncthreads();
    }

    // epilogue: y[998] from one extra MFMA pass over h_998 (in bcol[1])
    if (w6) {
        short8 B0 = *(const short8*)&bcol[1][e * BSTR + g4 * 8];
        short8 B1 = *(const short8*)&bcol[1][e * BSTR + 32 + g4 * 8];
        floatx4 acc = __builtin_amdgcn_mfma_f32_16x16x32_bf16(A0a, B0, bqa, 0, 0, 0);
        acc = __builtin_amdgcn_mfma_f32_16x16x32_bf16(A1a, B1, acc, 0, 0, 0);
        if (g4 == 3 && e < EPB)
            out[(size_t)(e0 + e) * SEQT + (SEQT - 1)] = acc[0] + bfc;
    }
}

extern "C" void kernel_launch(void* const* d_in, const int* in_sizes, int n_in,
                              void* d_out, int out_size, void* d_ws, size_t ws_size,
                              hipStream_t stream) {
    const float* x    = (const float*)d_in[0];
    const float* W_ih = (const float*)d_in[1];
    const float* W_hh = (const float*)d_in[2];
    const float* b_ih = (const float*)d_in[3];
    const float* b_hh = (const float*)d_in[4];
    const float* W_fc = (const float*)d_in[5];
    const float* b_fc = (const float*)d_in[6];
    float* out = (float*)d_out;

    __hip_bfloat16* A_ext = (__hip_bfloat16*)d_ws;   // 208*64*2 = 26.6 KB

    prep_kernel<<<(MR * 64 + 255) / 256, 256, 0, stream>>>(W_hh, W_ih, W_fc, A_ext);
    lstm_mfma_kernel<<<4096 / EPB, NTH, 0, stream>>>(x, b_ih, b_hh,
                                                     b_fc, A_ext, out);
}

// Round 9
// 436.231 us; speedup vs baseline: 2.0194x; 1.4610x over previous
//
#include <hip/hip_runtime.h>
#include <hip/hip_bf16.h>

#define HID   51
#define MR    208          // 204 gate rows + y row (204) padded to 13 tiles of 16
#define SEQT  999
#define CH    111          // 999 = 9 * 111
#define NCH   9
#define EPB   16           // batch elements per block -> 256 blocks, full-width lanes
#define XST   17           // x/y LDS stride (EPB+1)
#define NTH   448          // 7 waves: waves 0-5 = 2 tiles each, wave 6 = tile 12 + service
#define BSTR  72           // bcol row stride in halves (144 B: 16B-aligned, free 2-way)

typedef __attribute__((ext_vector_type(8))) short  short8;   // 8 bf16 = 4 VGPRs
typedef __attribute__((ext_vector_type(4))) float  floatx4;

// A_ext[208][64] bf16, row r = 4u+gate, PRE-SCALED by -log2(e) (i,f,o) or
// -2*log2(e) (g) so the MFMA output is directly an exp2 argument.
//   rows 0..203: cols 0..50 <- W_hh[gate*51+u][k], col 51 <- W_ih[gate*51+u]
//   row  204   : cols 0..50 <- W_fc[k] UNSCALED  (y_{t-1} falls out of the MFMA)
__global__ void prep_kernel(const float* __restrict__ W_hh,
                            const float* __restrict__ W_ih,
                            const float* __restrict__ W_fc,
                            __hip_bfloat16* __restrict__ A_ext)
{
    const float K1 = 1.442695040889f;
    int idx = blockIdx.x * blockDim.x + threadIdx.x;
    if (idx >= MR * 64) return;
    int r = idx >> 6, k = idx & 63;
    int u = r >> 2, gate = r & 3;
    float v = 0.f;
    if (r == 204) {
        if (k < HID) v = W_fc[k];
    } else if (u < HID) {
        float s = (gate == 2) ? (-2.f * K1) : (-K1);
        if (k < HID)      v = s * W_hh[(gate * HID + u) * HID + k];
        else if (k == 51) v = s * W_ih[gate * HID + u];
    }
    A_ext[idx] = __float2bfloat16(v);
}

__launch_bounds__(NTH)
__global__ void lstm_mfma_kernel(const float* __restrict__ x,
                                 const float* __restrict__ b_ih,
                                 const float* __restrict__ b_hh,
                                 const float* __restrict__ b_fc,
                                 const __hip_bfloat16* __restrict__ A_ext,
                                 float* __restrict__ out)
{
    __shared__ __hip_bfloat16 bcol[2][16 * BSTR];
    __shared__ float x_lds[(CH + 1) * XST];   // +1 lookahead for row-51 prewrite
    __shared__ float y_lds[CH * XST];         // slot tt holds y[t0 + tt - 1]

    const int tid  = threadIdx.x;
    const int w    = tid >> 6;    // 0..5 double-tile waves, 6 = tile-12 + service
    const int lane = tid & 63;
    const int e    = lane & 15;   // MFMA col — all 16 live
    const int g4   = lane >> 4;   // lane group
    const int e0   = blockIdx.x * EPB;
    const bool w6  = (w == 6);
    // wave 6 tile-12 units: 48+g4 for g4<3; g4==3 lanes own the y row (204)
    const int  uB6   = 48 + g4;
    const bool yln   = w6 && (g4 == 3);
    const bool xsv   = w6 && (g4 == 0);
    const int  wrow6 = (uB6 < HID) ? uB6 : 63;   // g4==3 -> dump row 63

    const float K1  = 1.442695040889f;
    const float K2N = -2.885390081777f;      // -2*log2(e)

    // waves 0-5: tiles Ta=2w, Tb=2w+1 -> units ua=8w+g4, ub=8w+4+g4 (all <48)
    short8  A0a = {0,0,0,0,0,0,0,0}, A1a = {0,0,0,0,0,0,0,0};
    short8  A0b = {0,0,0,0,0,0,0,0}, A1b = {0,0,0,0,0,0,0,0};
    floatx4 bqa = {0.f, 0.f, 0.f, 0.f}, bqb = {0.f, 0.f, 0.f, 0.f};
    float   csa = 0.f, csb = 0.f;            // cell states (pre-scaled)
    int ua = 0, ub = 0;

    if (!w6) {
        int Ta = 2 * w, Tb = 2 * w + 1;
        ua = 4 * Ta + g4; ub = 4 * Tb + g4;
        int ma = Ta * 16 + e, mb = Tb * 16 + e;
        A0a = *(const short8*)&A_ext[ma * 64 + g4 * 8];
        A1a = *(const short8*)&A_ext[ma * 64 + 32 + g4 * 8];
        A0b = *(const short8*)&A_ext[mb * 64 + g4 * 8];
        A1b = *(const short8*)&A_ext[mb * 64 + 32 + g4 * 8];
#pragma unroll
        for (int gg = 0; gg < 4; ++gg) {
            float s = (gg == 2) ? (-2.f * K1) : (-K1);
            bqa[gg] = s * (b_ih[gg * HID + ua] + b_hh[gg * HID + ua]);
            bqb[gg] = s * (b_ih[gg * HID + ub] + b_hh[gg * HID + ub]);
        }
    } else {
        int m = 12 * 16 + e;
        A0a = *(const short8*)&A_ext[m * 64 + g4 * 8];
        A1a = *(const short8*)&A_ext[m * 64 + 32 + g4 * 8];
        if (uB6 < HID) {
#pragma unroll
            for (int gg = 0; gg < 4; ++gg) {
                float s = (gg == 2) ? (-2.f * K1) : (-K1);
                bqa[gg] = s * (b_ih[gg * HID + uB6] + b_hh[gg * HID + uB6]);
            }
        }
    }

    for (int i = tid; i < 16 * BSTR; i += NTH) {
        bcol[0][i] = __float2bfloat16(0.f);
        bcol[1][i] = __float2bfloat16(0.f);
    }
    __syncthreads();   // zero-init fully ordered before x0 seed
    if (tid < EPB)
        bcol[0][tid * BSTR + 51] = __float2bfloat16(x[(size_t)(e0 + tid) * SEQT]);
    const float bfc = b_fc[0];

    __syncthreads();

    for (int tc = 0; tc < NCH; ++tc) {
        const int t0 = tc * CH;
        for (int i2 = tid; i2 < (CH + 1) * EPB; i2 += NTH) {
            int ee = i2 / (CH + 1), tt = i2 % (CH + 1);
            int t = t0 + tt;
            x_lds[tt * XST + ee] = (t < SEQT) ? x[(size_t)(e0 + ee) * SEQT + t] : 0.f;
        }
        __syncthreads();

        for (int tt = 0; tt < CH; ++tt) {
            const int t  = t0 + tt;
            const int rp = t & 1, wp = rp ^ 1;

            short8 B0 = *(const short8*)&bcol[rp][e * BSTR + g4 * 8];
            short8 B1 = *(const short8*)&bcol[rp][e * BSTR + 32 + g4 * 8];

            if (!w6) {
                // two independent tiles -> two ILP chains per wave
                floatx4 aa = __builtin_amdgcn_mfma_f32_16x16x32_bf16(A0a, B0, bqa, 0, 0, 0);
                floatx4 ab = __builtin_amdgcn_mfma_f32_16x16x32_bf16(A0b, B0, bqb, 0, 0, 0);
                aa = __builtin_amdgcn_mfma_f32_16x16x32_bf16(A1a, B1, aa, 0, 0, 0);
                ab = __builtin_amdgcn_mfma_f32_16x16x32_bf16(A1b, B1, ab, 0, 0, 0);

                float Eia = __builtin_amdgcn_exp2f(aa[0]);
                float Efa = __builtin_amdgcn_exp2f(aa[1]);
                float Ega = __builtin_amdgcn_exp2f(aa[2]);
                float Eoa = __builtin_amdgcn_exp2f(aa[3]);
                float Eib = __builtin_amdgcn_exp2f(ab[0]);
                float Efb = __builtin_amdgcn_exp2f(ab[1]);
                float Egb = __builtin_amdgcn_exp2f(ab[2]);
                float Eob = __builtin_amdgcn_exp2f(ab[3]);

                float sfa  = __builtin_amdgcn_rcpf(1.f + Efa);
                float sfb  = __builtin_amdgcn_rcpf(1.f + Efb);
                float Riga = __builtin_amdgcn_rcpf(fmaf(Eia, Ega, (Eia + Ega) + 1.f));
                float Rigb = __builtin_amdgcn_rcpf(fmaf(Eib, Egb, (Eib + Egb) + 1.f));
                csa = fmaf(sfa, csa, K2N * ((1.f - Ega) * Riga));
                csb = fmaf(sfb, csb, K2N * ((1.f - Egb) * Rigb));
                float Eca = __builtin_amdgcn_exp2f(csa);
                float Ecb = __builtin_amdgcn_exp2f(csb);
                float Roca = __builtin_amdgcn_rcpf(fmaf(Eoa, Eca, (Eoa + Eca) + 1.f));
                float Rocb = __builtin_amdgcn_rcpf(fmaf(Eob, Ecb, (Eob + Ecb) + 1.f));
                float ha = (1.f - Eca) * Roca;
                float hb = (1.f - Ecb) * Rocb;

                bcol[wp][e * BSTR + ua] = __float2bfloat16(ha);
                bcol[wp][e * BSTR + ub] = __float2bfloat16(hb);
            } else {
                floatx4 acc = __builtin_amdgcn_mfma_f32_16x16x32_bf16(A0a, B0, bqa, 0, 0, 0);
                acc = __builtin_amdgcn_mfma_f32_16x16x32_bf16(A1a, B1, acc, 0, 0, 0);

                float Ei = __builtin_amdgcn_exp2f(acc[0]);
                float Ef = __builtin_amdgcn_exp2f(acc[1]);
                float Eg = __builtin_amdgcn_exp2f(acc[2]);
                float Eo = __builtin_amdgcn_exp2f(acc[3]);
                float sf  = __builtin_amdgcn_rcpf(1.f + Ef);
                float Rig = __builtin_amdgcn_rcpf(fmaf(Ei, Eg, (Ei + Eg) + 1.f));
                csa = fmaf(sf, csa, K2N * ((1.f - Eg) * Rig));
                float Ec = __builtin_amdgcn_exp2f(csa);
                float Roc = __builtin_amdgcn_rcpf(fmaf(Eo, Ec, (Eo + Ec) + 1.f));
                float h = (1.f - Ec) * Roc;

                bcol[wp][e * BSTR + wrow6] = __float2bfloat16((uB6 < HID) ? h : 0.f);
                if (yln) y_lds[tt * XST + e] = acc[0] + bfc;   // y[t-1], free
                if (xsv) bcol[wp][e * BSTR + 51] =
                             __float2bfloat16(x_lds[(tt + 1) * XST + e]);
            }

            __syncthreads();   // the ONE barrier per step
        }
        __syncthreads();

        // flush y[t0-1 .. t0+CH-2] (slot tt <-> t0+tt-1); skip t = -1
        for (int i2 = tid; i2 < CH * EPB; i2 += NTH) {
            int ee = i2 / CH, tt = i2 % CH;
            int t = t0 + tt - 1;
            if (t >= 0)
                out[(size_t)(e0 + ee) * SEQT + t] = y_lds[tt * XST + ee];
        }
        __syncthreads();
    }

    // epilogue: y[998] from one extra MFMA pass over h_998 (in bcol[1])
    if (w6) {
        short8 B0 = *(const short8*)&bcol[1][e * BSTR + g4 * 8];
        short8 B1 = *(const short8*)&bcol[1][e * BSTR + 32 + g4 * 8];
        floatx4 acc = __builtin_amdgcn_mfma_f32_16x16x32_bf16(A0a, B0, bqa, 0, 0, 0);
        acc = __builtin_amdgcn_mfma_f32_16x16x32_bf16(A1a, B1, acc, 0, 0, 0);
        if (g4 == 3)
            out[(size_t)(e0 + e) * SEQT + (SEQT - 1)] = acc[0] + bfc;
    }
}

extern "C" void kernel_launch(void* const* d_in, const int* in_sizes, int n_in,
                              void* d_out, int out_size, void* d_ws, size_t ws_size,
                              hipStream_t stream) {
    const float* x    = (const float*)d_in[0];
    const float* W_ih = (const float*)d_in[1];
    const float* W_hh = (const float*)d_in[2];
    const float* b_ih = (const float*)d_in[3];
    const float* b_hh = (const float*)d_in[4];
    const float* W_fc = (const float*)d_in[5];
    const float* b_fc = (const float*)d_in[6];
    float* out = (float*)d_out;

    __hip_bfloat16* A_ext = (__hip_bfloat16*)d_ws;   // 208*64*2 = 26.6 KB

    prep_kernel<<<(MR * 64 + 255) / 256, 256, 0, stream>>>(W_hh, W_ih, W_fc, A_ext);
    lstm_mfma_kernel<<<4096 / EPB, NTH, 0, stream>>>(x, b_ih, b_hh,
                                                     b_fc, A_ext, out);
}